// Round 7
// baseline (1658.040 us; speedup 1.0000x reference)
//
#include <hip/hip_runtime.h>
#include <hip/hip_fp16.h>

// Masked LSTM, T=512 B=64 D=512 H=512 — single fused persistent kernel.
// Structure = round-6-verified Phase B (8 waves/512 thr, W_hh fp16 in LDS,
// 4 gate tiles x 2 k-splits, coalesced LDS staging of h, tid<64 flag spin,
// out-stores + prefetch in the spin shadow) PLUS Phase A folded in:
//   x_proj for step ts+1 is computed during step ts's spin shadow.
//   W_ih slice (64x512 fp16) lives in LDS next to W_hh. Inputs row-slab
//   (8 batches x 512 fp32 = 16KB) is staged into the (free-after-MFMA) hl
//   area, and each wave runs 8 x-MFMAs into xacc — which SEEDS the h-matmul
//   accumulator next step (identical fragment layout -> part[] reduce handles
//   x+h together, zero extra exchange). Bias is added in the epilogue.
//   x_proj never exists as an fp16 intermediate (stays fp32 in acc).

#define T_DIM 512
#define B_DIM 64
#define D_DIM 512
#define H_DIM 512
#define M_DIM (T_DIM * B_DIM)

#define NGROUP 8
#define BPG 32
#define NBLK (NGROUP * BPG)     // 256
#define NTHR 512
#define WS 520                  // LDS row stride in fp16 elements (512 + 8 pad)

typedef __attribute__((ext_vector_type(8))) _Float16 half8;
typedef __attribute__((ext_vector_type(2))) __fp16 fp16x2;
typedef __attribute__((ext_vector_type(4))) float float4v;

#define AT_LD_I(p)    __hip_atomic_load((p), __ATOMIC_RELAXED, __HIP_MEMORY_SCOPE_AGENT)
#define AT_ST_I(p, v) __hip_atomic_store((p), (v), __ATOMIC_RELAXED, __HIP_MEMORY_SCOPE_AGENT)
#define AT_LD64(p)    __hip_atomic_load((p), __ATOMIC_RELAXED, __HIP_MEMORY_SCOPE_AGENT)
#define AT_ST64(p, v) __hip_atomic_store((p), (v), __ATOMIC_RELAXED, __HIP_MEMORY_SCOPE_AGENT)

__device__ __forceinline__ float sigf(float x) { return 1.0f / (1.0f + __expf(-x)); }
__device__ __forceinline__ float tanhfast(float x) { return 2.0f / (1.0f + __expf(-2.0f * x)) - 1.0f; }
__device__ __forceinline__ unsigned short f2h(float x) {
  return __builtin_bit_cast(unsigned short, (_Float16)x);
}
__device__ __forceinline__ unsigned pk2h(float a, float b) {
  fp16x2 h = __builtin_amdgcn_cvt_pkrtz(a, b);
  return __builtin_bit_cast(unsigned, h);
}

// ---------------------------------------------------------------- fused LSTM
__global__ __launch_bounds__(NTHR) void lstm_seq(
    const float* __restrict__ inputs, const float* __restrict__ mask,
    const float* __restrict__ h0, const float* __restrict__ Whh,
    const float* __restrict__ Wih, const float* __restrict__ b_ih,
    const float* __restrict__ b_hh,
    float* __restrict__ out, unsigned short* __restrict__ hbuf,
    int* slot_base) {
  extern __shared__ char smemc[];
  unsigned short* Wl = (unsigned short*)smemc;     // W_hh [r][k] 64 x WS = 66560 B
  unsigned short* Xw = Wl + 64 * WS;               // W_ih [r][k] 64 x WS = 66560 B
  unsigned short* hl = Xw + 64 * WS;               // h / x staging [m][k] 16 x WS = 16640 B
  float* part = (float*)(hl + 16 * WS);            // 8 waves x 256 f32 = 8192 B
  // total 157,952 B

  const int tid = threadIdx.x;
  const int blk = blockIdx.x;
  const int grp = blk & 7;
  const int rank = blk >> 3;
  const int bbase = grp * 8;
  const int jbase = rank * 16;
  int* slots = (int*)((char*)slot_base + grp * 128);

  // ---- W_hh + W_ih slices -> LDS fp16. r = q*16 + jl <-> global row q*512+jbase+jl.
  for (int idx = tid; idx < 64 * 128; idx += NTHR) {
    int r = idx >> 7;
    int k4 = (idx & 127) << 2;
    int grow = (r >> 4) * H_DIM + jbase + (r & 15);
    float4 wv = *(const float4*)(Whh + (size_t)grow * H_DIM + k4);
    *(uint2*)(Wl + r * WS + k4) = make_uint2(pk2h(wv.x, wv.y), pk2h(wv.z, wv.w));
    float4 xv = *(const float4*)(Wih + (size_t)grow * D_DIM + k4);
    *(uint2*)(Xw + r * WS + k4) = make_uint2(pk2h(xv.x, xv.y), pk2h(xv.z, xv.w));
  }

  const int eb = tid >> 4, ejl = tid & 15;   // tid<128: (batch 0..7, h-dim 0..15)
  const int bglob = bbase + eb;
  const int jglob = jbase + ejl;
  float h0v = 0.0f, cval = 0.0f, mval = 1.f;
  float bi_ = 0.f, bf_ = 0.f, bg_ = 0.f, bo_ = 0.f;
  if (tid < 128) {
    h0v = h0[bglob * H_DIM + jglob];
    cval = h0v;
    bi_ = b_ih[0 * H_DIM + jglob] + b_hh[0 * H_DIM + jglob];
    bf_ = b_ih[1 * H_DIM + jglob] + b_hh[1 * H_DIM + jglob];
    bg_ = b_ih[2 * H_DIM + jglob] + b_hh[2 * H_DIM + jglob];
    bo_ = b_ih[3 * H_DIM + jglob] + b_hh[3 * H_DIM + jglob];
  }

  // ---- publish h0 as u64 (4 packed fp16) into buffer 0
  {
    int mybits = (tid < 128) ? (int)f2h(h0v) : 0;
    int nb1 = __shfl_down(mybits, 1, 64);
    int nb2 = __shfl_down(mybits, 2, 64);
    int nb3 = __shfl_down(mybits, 3, 64);
    if (tid < 128 && ((ejl & 3) == 0)) {
      unsigned lo = (unsigned)mybits | ((unsigned)nb1 << 16);
      unsigned hi = (unsigned)nb2 | ((unsigned)nb3 << 16);
      AT_ST64((unsigned long long*)hbuf + bglob * 128 + (jglob >> 2),
              ((unsigned long long)hi << 32) | lo);
    }
  }
  __syncthreads();   // drains vmcnt(0): publishes at coherence point
  if (tid == 0) AT_ST_I(&slots[rank], 1);
  if (tid < 128) mval = mask[bglob];

  const int w = tid >> 6;        // wave id
  const int lane = tid & 63;
  const int q = w & 3;           // gate tile (i,f,g,o)
  const int ks = w >> 2;         // k-split 0..1 (256 k each)
  const int am = lane & 15;      // A row (batch, padded to 16)
  const int koct = (lane >> 4) * 8;
  const int br = q * 16 + (lane & 15);   // W row in LDS

  // ---- stage x(0) into hl + x-MFMA -> xacc (shadow of the h0 barrier)
  float4v xacc = {0.f, 0.f, 0.f, 0.f};
  {
    const float* xin = inputs + (size_t)bbase * D_DIM;  // ts=0 slab
#pragma unroll
    for (int i = 0; i < 4; ++i) {
      int idx = tid + i * NTHR;         // 0..2047 (u32 granule)
      int r = idx >> 8;                 // batch 0..7
      int cl = idx & 255;               // u32 col
      float2 xv = *(const float2*)(xin + (size_t)r * D_DIM + cl * 2);
      ((unsigned*)hl)[r * (WS / 2) + cl] = pk2h(xv.x, xv.y);
    }
    __syncthreads();
#pragma unroll
    for (int kc = 0; kc < 8; ++kc) {
      int k = ks * 256 + kc * 32 + koct;
      half8 a = *(const half8*)((const _Float16*)hl + am * WS + k);
      half8 b8 = *(const half8*)((const _Float16*)Xw + br * WS + k);
      xacc = __builtin_amdgcn_mfma_f32_16x16x32_f16(a, b8, xacc, 0, 0, 0);
    }
  }
  if (tid < 64) {
    int v;
    do {
      v = (tid < BPG) ? AT_LD_I(&slots[tid]) : 1;
      if (__all(v >= 1)) break;
      __builtin_amdgcn_s_sleep(2);
    } while (true);
  }
  __syncthreads();
  __asm__ volatile("" ::: "memory");

  for (int ts = 0; ts < T_DIM; ++ts) {
    const unsigned long long* cur64 =
        (const unsigned long long*)hbuf + (ts & 1) * (B_DIM * H_DIM / 4) +
        (size_t)bbase * 128;
    unsigned long long* nxt64 =
        (unsigned long long*)hbuf + ((ts + 1) & 1) * (B_DIM * H_DIM / 4);

    // stage h (8 batches x 512 f16 = 8KB): 512 thr x 2 coalesced u64, LDS [8][520]
#pragma unroll
    for (int i = 0; i < 2; ++i) {
      int v = tid + i * NTHR;                       // u64 index 0..1023
      unsigned long long u = AT_LD64(cur64 + v);
      ((unsigned long long*)hl)[(v >> 7) * 130 + (v & 127)] = u;
    }
    __syncthreads();

    // h-MFMA seeded with x-partials: D[m][n] = xacc + sum_k h[m][k]*W[q*16+n][k]
    float4v acc = xacc;
#pragma unroll
    for (int kc = 0; kc < 8; ++kc) {
      int k = ks * 256 + kc * 32 + koct;
      half8 a = *(const half8*)((const _Float16*)hl + am * WS + k);
      half8 b8 = *(const half8*)((const _Float16*)Wl + br * WS + k);
      acc = __builtin_amdgcn_mfma_f32_16x16x32_f16(a, b8, acc, 0, 0, 0);
    }
    // partials -> LDS: part[w][m][n]
#pragma unroll
    for (int reg = 0; reg < 4; ++reg) {
      int m = (lane >> 4) * 4 + reg;
      part[w * 256 + m * 16 + (lane & 15)] = acc[reg];
    }
    __syncthreads();

    // epilogue (tid<128): sum the two k-splits + bias; gates; publish
    float hnew = 0.f;
    if (tid < 128) {
      int o = eb * 16 + ejl;
      float iv = sigf(part[0 * 256 + o] + part[4 * 256 + o] + bi_);
      float fv = sigf(part[1 * 256 + o] + part[5 * 256 + o] + bf_);
      float gv = tanhfast(part[2 * 256 + o] + part[6 * 256 + o] + bg_);
      float ov = sigf(part[3 * 256 + o] + part[7 * 256 + o] + bo_);
      float cn = fv * cval + iv * gv;
      float hn = ov * tanhfast(cn);
      hnew = hn * mval + h0v * (1.0f - mval);
      cval = cn * mval + h0v * (1.0f - mval);
    }
    {
      int mybits = (tid < 128) ? (int)f2h(hnew) : 0;
      int nb1 = __shfl_down(mybits, 1, 64);
      int nb2 = __shfl_down(mybits, 2, 64);
      int nb3 = __shfl_down(mybits, 3, 64);
      if (tid < 128 && ((ejl & 3) == 0)) {
        unsigned lo = (unsigned)mybits | ((unsigned)nb1 << 16);
        unsigned hi = (unsigned)nb2 | ((unsigned)nb3 << 16);
        AT_ST64(nxt64 + bglob * 128 + (jglob >> 2),
                ((unsigned long long)hi << 32) | lo);
      }
    }
    __syncthreads();   // vmcnt drain -> publishes visible before flag
    if (tid == 0) AT_ST_I(&slots[rank], ts + 2);

    // ---- spin shadow: stage x(ts+1), x-MFMA, out stores, mask prefetch
    if (ts + 1 < T_DIM) {
      const float* xin = inputs + ((size_t)(ts + 1) * B_DIM + bbase) * D_DIM;
#pragma unroll
      for (int i = 0; i < 4; ++i) {
        int idx = tid + i * NTHR;
        int r = idx >> 8;
        int cl = idx & 255;
        float2 xv = *(const float2*)(xin + (size_t)r * D_DIM + cl * 2);
        ((unsigned*)hl)[r * (WS / 2) + cl] = pk2h(xv.x, xv.y);
      }
      __syncthreads();   // stage-x visible to x-MFMA reads (in shadow)
      if (tid < 128) {
        out[((size_t)ts * B_DIM + bglob) * H_DIM + jglob] = hnew;
        mval = mask[(ts + 1) * B_DIM + bglob];
      }
      float4v xa = {0.f, 0.f, 0.f, 0.f};
#pragma unroll
      for (int kc = 0; kc < 8; ++kc) {
        int k = ks * 256 + kc * 32 + koct;
        half8 a = *(const half8*)((const _Float16*)hl + am * WS + k);
        half8 b8 = *(const half8*)((const _Float16*)Xw + br * WS + k);
        xa = __builtin_amdgcn_mfma_f32_16x16x32_f16(a, b8, xa, 0, 0, 0);
      }
      xacc = xa;
    } else if (tid < 128) {
      out[((size_t)ts * B_DIM + bglob) * H_DIM + jglob] = hnew;
      out[(size_t)T_DIM * B_DIM * H_DIM + bglob * H_DIM + jglob] = hnew;
      out[(size_t)T_DIM * B_DIM * H_DIM + B_DIM * H_DIM + bglob * H_DIM + jglob] = cval;
    }

    if (tid < 64) {
      int v;
      do {
        v = (tid < BPG) ? AT_LD_I(&slots[tid]) : (ts + 2);
        if (__all(v >= ts + 2)) break;
        __builtin_amdgcn_s_sleep(2);
      } while (true);
    }
    __syncthreads();
    __asm__ volatile("" ::: "memory");
  }
}

// ---------------------------------------------------------------- launch
extern "C" void kernel_launch(void* const* d_in, const int* in_sizes, int n_in,
                              void* d_out, int out_size, void* d_ws, size_t ws_size,
                              hipStream_t stream) {
  const float* inputs = (const float*)d_in[0];
  const float* maskp  = (const float*)d_in[1];
  const float* h0     = (const float*)d_in[2];
  const float* W_ih   = (const float*)d_in[3];
  const float* W_hh   = (const float*)d_in[4];
  const float* b_ih   = (const float*)d_in[5];
  const float* b_hh   = (const float*)d_in[6];
  float* out = (float*)d_out;

  char* ws = (char*)d_ws;
  int* slot_base = (int*)ws;                            // 8 groups x 32 slots (128B apart)
  unsigned short* hbuf = (unsigned short*)(ws + 4096);  // fp16 h double buffer, 128KB

  (void)hipMemsetAsync(d_ws, 0, 4096, stream);

  size_t ldsB = (size_t)(64 * WS * 2 * 2 + 16 * WS * 2 + 2048 * 4);  // 157,952 B

  lstm_seq<<<NBLK, NTHR, ldsB, stream>>>(inputs, maskp, h0, W_hh, W_ih, b_ih, b_hh,
                                         out, hbuf, slot_base);

  (void)in_sizes; (void)n_in; (void)out_size; (void)ws_size;
}

// Round 8
// 1352.296 us; speedup vs baseline: 1.2261x; 1.2261x over previous
//
#include <hip/hip_runtime.h>
#include <hip/hip_fp16.h>

// Masked LSTM, T=512 B=64 D=512 H=512 — single fused persistent kernel.
// Round-6-verified recurrence structure (8 waves/512 thr, W_hh fp16 in LDS,
// 4 gate tiles x 2 k-splits, coalesced LDS staging of h, tid<64 flag spin)
// with Phase A folded in T14-style (issue-early / consume-late):
//   - inputs(ts+1) global loads are ISSUED at the top of step ts (into regs),
//     overlapping h-MFMA + epilogue (~2000 cy) with their HBM latency.
//   - in the spin shadow: pk2h -> ds_write x -> barrier -> 8 x-MFMAs -> xacc.
//   - xacc SEEDS the h-matmul accumulator next step (identical fragment
//     layout -> part[] reduce handles x+h together, zero extra exchange).
//   - x_proj never exists as a stored intermediate (stays fp32 in acc).
//   W_ih slice (64x512 fp16) lives in LDS next to W_hh (157,952 B total).

#define T_DIM 512
#define B_DIM 64
#define D_DIM 512
#define H_DIM 512
#define M_DIM (T_DIM * B_DIM)

#define NGROUP 8
#define BPG 32
#define NBLK (NGROUP * BPG)     // 256
#define NTHR 512
#define WS 520                  // LDS row stride in fp16 elements (512 + 8 pad)

typedef __attribute__((ext_vector_type(8))) _Float16 half8;
typedef __attribute__((ext_vector_type(2))) __fp16 fp16x2;
typedef __attribute__((ext_vector_type(4))) float float4v;

#define AT_LD_I(p)    __hip_atomic_load((p), __ATOMIC_RELAXED, __HIP_MEMORY_SCOPE_AGENT)
#define AT_ST_I(p, v) __hip_atomic_store((p), (v), __ATOMIC_RELAXED, __HIP_MEMORY_SCOPE_AGENT)
#define AT_LD64(p)    __hip_atomic_load((p), __ATOMIC_RELAXED, __HIP_MEMORY_SCOPE_AGENT)
#define AT_ST64(p, v) __hip_atomic_store((p), (v), __ATOMIC_RELAXED, __HIP_MEMORY_SCOPE_AGENT)

__device__ __forceinline__ float sigf(float x) { return 1.0f / (1.0f + __expf(-x)); }
__device__ __forceinline__ float tanhfast(float x) { return 2.0f / (1.0f + __expf(-2.0f * x)) - 1.0f; }
__device__ __forceinline__ unsigned short f2h(float x) {
  return __builtin_bit_cast(unsigned short, (_Float16)x);
}
__device__ __forceinline__ unsigned pk2h(float a, float b) {
  fp16x2 h = __builtin_amdgcn_cvt_pkrtz(a, b);
  return __builtin_bit_cast(unsigned, h);
}

// ---------------------------------------------------------------- fused LSTM
__global__ __launch_bounds__(NTHR) void lstm_seq(
    const float* __restrict__ inputs, const float* __restrict__ mask,
    const float* __restrict__ h0, const float* __restrict__ Whh,
    const float* __restrict__ Wih, const float* __restrict__ b_ih,
    const float* __restrict__ b_hh,
    float* __restrict__ out, unsigned short* __restrict__ hbuf,
    int* slot_base) {
  extern __shared__ char smemc[];
  unsigned short* Wl = (unsigned short*)smemc;     // W_hh [r][k] 64 x WS = 66560 B
  unsigned short* Xw = Wl + 64 * WS;               // W_ih [r][k] 64 x WS = 66560 B
  unsigned short* hl = Xw + 64 * WS;               // h / x staging [m][k] 16 x WS = 16640 B
  float* part = (float*)(hl + 16 * WS);            // 8 waves x 256 f32 = 8192 B
  // total 157,952 B

  const int tid = threadIdx.x;
  const int blk = blockIdx.x;
  const int grp = blk & 7;
  const int rank = blk >> 3;
  const int bbase = grp * 8;
  const int jbase = rank * 16;
  int* slots = (int*)((char*)slot_base + grp * 128);

  // ---- W_hh + W_ih slices -> LDS fp16. r = q*16 + jl <-> global row q*512+jbase+jl.
  for (int idx = tid; idx < 64 * 128; idx += NTHR) {
    int r = idx >> 7;
    int k4 = (idx & 127) << 2;
    int grow = (r >> 4) * H_DIM + jbase + (r & 15);
    float4 wv = *(const float4*)(Whh + (size_t)grow * H_DIM + k4);
    *(uint2*)(Wl + r * WS + k4) = make_uint2(pk2h(wv.x, wv.y), pk2h(wv.z, wv.w));
    float4 xv = *(const float4*)(Wih + (size_t)grow * D_DIM + k4);
    *(uint2*)(Xw + r * WS + k4) = make_uint2(pk2h(xv.x, xv.y), pk2h(xv.z, xv.w));
  }

  const int eb = tid >> 4, ejl = tid & 15;   // tid<128: (batch 0..7, h-dim 0..15)
  const int bglob = bbase + eb;
  const int jglob = jbase + ejl;
  float h0v = 0.0f, cval = 0.0f, mval = 1.f;
  float bi_ = 0.f, bf_ = 0.f, bg_ = 0.f, bo_ = 0.f;
  if (tid < 128) {
    h0v = h0[bglob * H_DIM + jglob];
    cval = h0v;
    bi_ = b_ih[0 * H_DIM + jglob] + b_hh[0 * H_DIM + jglob];
    bf_ = b_ih[1 * H_DIM + jglob] + b_hh[1 * H_DIM + jglob];
    bg_ = b_ih[2 * H_DIM + jglob] + b_hh[2 * H_DIM + jglob];
    bo_ = b_ih[3 * H_DIM + jglob] + b_hh[3 * H_DIM + jglob];
  }

  // per-thread x-stage geometry: thread covers 4 (row, col-u32) slots
  const int xr0r = tid >> 8,            xr0c = tid & 255;          // idx = tid
  const int xr1r = (tid + 512) >> 8,    xr1c = tid & 255;          // idx = tid+512
  const int xr2r = (tid + 1024) >> 8,   xr2c = tid & 255;
  const int xr3r = (tid + 1536) >> 8,   xr3c = tid & 255;

  // ---- publish h0 as u64 (4 packed fp16) into buffer 0
  {
    int mybits = (tid < 128) ? (int)f2h(h0v) : 0;
    int nb1 = __shfl_down(mybits, 1, 64);
    int nb2 = __shfl_down(mybits, 2, 64);
    int nb3 = __shfl_down(mybits, 3, 64);
    if (tid < 128 && ((ejl & 3) == 0)) {
      unsigned lo = (unsigned)mybits | ((unsigned)nb1 << 16);
      unsigned hi = (unsigned)nb2 | ((unsigned)nb3 << 16);
      AT_ST64((unsigned long long*)hbuf + bglob * 128 + (jglob >> 2),
              ((unsigned long long)hi << 32) | lo);
    }
  }
  __syncthreads();   // drains vmcnt(0): publishes at coherence point
  if (tid == 0) AT_ST_I(&slots[rank], 1);
  if (tid < 128) mval = mask[bglob];

  const int w = tid >> 6;        // wave id
  const int lane = tid & 63;
  const int q = w & 3;           // gate tile (i,f,g,o)
  const int ks = w >> 2;         // k-split 0..1 (256 k each)
  const int am = lane & 15;      // A row (batch, padded to 16)
  const int koct = (lane >> 4) * 8;
  const int br = q * 16 + (lane & 15);   // W row in LDS

  // ---- stage x(0) into hl + x-MFMA -> xacc (shadow of the h0 barrier)
  float4v xacc = {0.f, 0.f, 0.f, 0.f};
  {
    const float* xin = inputs + (size_t)bbase * D_DIM;  // ts=0 slab
    float2 a0 = *(const float2*)(xin + (size_t)xr0r * D_DIM + xr0c * 2);
    float2 a1 = *(const float2*)(xin + (size_t)xr1r * D_DIM + xr1c * 2);
    float2 a2 = *(const float2*)(xin + (size_t)xr2r * D_DIM + xr2c * 2);
    float2 a3 = *(const float2*)(xin + (size_t)xr3r * D_DIM + xr3c * 2);
    ((unsigned*)hl)[xr0r * (WS / 2) + xr0c] = pk2h(a0.x, a0.y);
    ((unsigned*)hl)[xr1r * (WS / 2) + xr1c] = pk2h(a1.x, a1.y);
    ((unsigned*)hl)[xr2r * (WS / 2) + xr2c] = pk2h(a2.x, a2.y);
    ((unsigned*)hl)[xr3r * (WS / 2) + xr3c] = pk2h(a3.x, a3.y);
    __syncthreads();
#pragma unroll
    for (int kc = 0; kc < 8; ++kc) {
      int k = ks * 256 + kc * 32 + koct;
      half8 a = *(const half8*)((const _Float16*)hl + am * WS + k);
      half8 b8 = *(const half8*)((const _Float16*)Xw + br * WS + k);
      xacc = __builtin_amdgcn_mfma_f32_16x16x32_f16(a, b8, xacc, 0, 0, 0);
    }
  }
  if (tid < 64) {
    int v;
    do {
      v = (tid < BPG) ? AT_LD_I(&slots[tid]) : 1;
      if (__all(v >= 1)) break;
      __builtin_amdgcn_s_sleep(2);
    } while (true);
  }
  __syncthreads();
  __asm__ volatile("" ::: "memory");

  for (int ts = 0; ts < T_DIM; ++ts) {
    const unsigned long long* cur64 =
        (const unsigned long long*)hbuf + (ts & 1) * (B_DIM * H_DIM / 4) +
        (size_t)bbase * 128;
    unsigned long long* nxt64 =
        (unsigned long long*)hbuf + ((ts + 1) & 1) * (B_DIM * H_DIM / 4);

    // ---- issue h-stage loads (flag-ordered) and x(ts+1) loads (T14: early)
    unsigned long long hld0 = AT_LD64(cur64 + tid);
    unsigned long long hld1 = AT_LD64(cur64 + tid + NTHR);
    const int xts = (ts + 1 < T_DIM) ? (ts + 1) : ts;   // clamp: keep loads valid
    const float* xin = inputs + ((size_t)xts * B_DIM + bbase) * D_DIM;
    float2 a0 = *(const float2*)(xin + (size_t)xr0r * D_DIM + xr0c * 2);
    float2 a1 = *(const float2*)(xin + (size_t)xr1r * D_DIM + xr1c * 2);
    float2 a2 = *(const float2*)(xin + (size_t)xr2r * D_DIM + xr2c * 2);
    float2 a3 = *(const float2*)(xin + (size_t)xr3r * D_DIM + xr3c * 2);

    // h -> LDS [8][520] (compiler waits only the h loads; x stays in flight)
    ((unsigned long long*)hl)[(tid >> 7) * 130 + (tid & 127)] = hld0;
    {
      int v = tid + NTHR;
      ((unsigned long long*)hl)[(v >> 7) * 130 + (v & 127)] = hld1;
    }
    __syncthreads();

    // h-MFMA seeded with x-partials: D[m][n] = xacc + sum_k h[m][k]*W[q*16+n][k]
    float4v acc = xacc;
#pragma unroll
    for (int kc = 0; kc < 8; ++kc) {
      int k = ks * 256 + kc * 32 + koct;
      half8 a = *(const half8*)((const _Float16*)hl + am * WS + k);
      half8 b8 = *(const half8*)((const _Float16*)Wl + br * WS + k);
      acc = __builtin_amdgcn_mfma_f32_16x16x32_f16(a, b8, acc, 0, 0, 0);
    }
    // partials -> LDS: part[w][m][n]
#pragma unroll
    for (int reg = 0; reg < 4; ++reg) {
      int m = (lane >> 4) * 4 + reg;
      part[w * 256 + m * 16 + (lane & 15)] = acc[reg];
    }
    __syncthreads();

    // epilogue (tid<128): sum the two k-splits + bias; gates; publish
    float hnew = 0.f;
    if (tid < 128) {
      int o = eb * 16 + ejl;
      float iv = sigf(part[0 * 256 + o] + part[4 * 256 + o] + bi_);
      float fv = sigf(part[1 * 256 + o] + part[5 * 256 + o] + bf_);
      float gv = tanhfast(part[2 * 256 + o] + part[6 * 256 + o] + bg_);
      float ov = sigf(part[3 * 256 + o] + part[7 * 256 + o] + bo_);
      float cn = fv * cval + iv * gv;
      float hn = ov * tanhfast(cn);
      hnew = hn * mval + h0v * (1.0f - mval);
      cval = cn * mval + h0v * (1.0f - mval);
    }
    {
      int mybits = (tid < 128) ? (int)f2h(hnew) : 0;
      int nb1 = __shfl_down(mybits, 1, 64);
      int nb2 = __shfl_down(mybits, 2, 64);
      int nb3 = __shfl_down(mybits, 3, 64);
      if (tid < 128 && ((ejl & 3) == 0)) {
        unsigned lo = (unsigned)mybits | ((unsigned)nb1 << 16);
        unsigned hi = (unsigned)nb2 | ((unsigned)nb3 << 16);
        AT_ST64(nxt64 + bglob * 128 + (jglob >> 2),
                ((unsigned long long)hi << 32) | lo);
      }
    }
    __syncthreads();   // vmcnt drain -> publishes (and x loads) complete
    if (tid == 0) AT_ST_I(&slots[rank], ts + 2);

    // ---- spin shadow: x already in regs -> pk2h + ds_write + x-MFMA
    if (ts + 1 < T_DIM) {
      ((unsigned*)hl)[xr0r * (WS / 2) + xr0c] = pk2h(a0.x, a0.y);
      ((unsigned*)hl)[xr1r * (WS / 2) + xr1c] = pk2h(a1.x, a1.y);
      ((unsigned*)hl)[xr2r * (WS / 2) + xr2c] = pk2h(a2.x, a2.y);
      ((unsigned*)hl)[xr3r * (WS / 2) + xr3c] = pk2h(a3.x, a3.y);
      __syncthreads();   // stage-x visible to x-MFMA reads (in shadow)
      if (tid < 128) {
        out[((size_t)ts * B_DIM + bglob) * H_DIM + jglob] = hnew;
        mval = mask[(ts + 1) * B_DIM + bglob];
      }
      float4v xa = {0.f, 0.f, 0.f, 0.f};
#pragma unroll
      for (int kc = 0; kc < 8; ++kc) {
        int k = ks * 256 + kc * 32 + koct;
        half8 a = *(const half8*)((const _Float16*)hl + am * WS + k);
        half8 b8 = *(const half8*)((const _Float16*)Xw + br * WS + k);
        xa = __builtin_amdgcn_mfma_f32_16x16x32_f16(a, b8, xa, 0, 0, 0);
      }
      xacc = xa;
    } else if (tid < 128) {
      out[((size_t)ts * B_DIM + bglob) * H_DIM + jglob] = hnew;
      out[(size_t)T_DIM * B_DIM * H_DIM + bglob * H_DIM + jglob] = hnew;
      out[(size_t)T_DIM * B_DIM * H_DIM + B_DIM * H_DIM + bglob * H_DIM + jglob] = cval;
    }

    if (tid < 64) {
      int v;
      do {
        v = (tid < BPG) ? AT_LD_I(&slots[tid]) : (ts + 2);
        if (__all(v >= ts + 2)) break;
        __builtin_amdgcn_s_sleep(2);
      } while (true);
    }
    __syncthreads();
    __asm__ volatile("" ::: "memory");
  }
}

// ---------------------------------------------------------------- launch
extern "C" void kernel_launch(void* const* d_in, const int* in_sizes, int n_in,
                              void* d_out, int out_size, void* d_ws, size_t ws_size,
                              hipStream_t stream) {
  const float* inputs = (const float*)d_in[0];
  const float* maskp  = (const float*)d_in[1];
  const float* h0     = (const float*)d_in[2];
  const float* W_ih   = (const float*)d_in[3];
  const float* W_hh   = (const float*)d_in[4];
  const float* b_ih   = (const float*)d_in[5];
  const float* b_hh   = (const float*)d_in[6];
  float* out = (float*)d_out;

  char* ws = (char*)d_ws;
  int* slot_base = (int*)ws;                            // 8 groups x 32 slots (128B apart)
  unsigned short* hbuf = (unsigned short*)(ws + 4096);  // fp16 h double buffer, 128KB

  (void)hipMemsetAsync(d_ws, 0, 4096, stream);

  size_t ldsB = (size_t)(64 * WS * 2 * 2 + 16 * WS * 2 + 2048 * 4);  // 157,952 B

  lstm_seq<<<NBLK, NTHR, ldsB, stream>>>(inputs, maskp, h0, W_hh, W_ih, b_ih, b_hh,
                                         out, hbuf, slot_base);

  (void)in_sizes; (void)n_in; (void)out_size; (void)ws_size;
}